// Round 2
// baseline (392.433 us; speedup 1.0000x reference)
//
#include <hip/hip_runtime.h>
#include <hip/hip_bf16.h>

#define NQ   14
#define DIM  16384      // 2^14
#define BLK  1024
#define WMUL 0.6324555320336759f  // sqrt(2/5)

struct alignas(8) C2 { float x, y; };
__device__ inline C2 cmul(C2 a, C2 b){ return C2{a.x*b.x - a.y*b.y, a.x*b.y + a.y*b.x}; }
__device__ inline C2 cadd(C2 a, C2 b){ return C2{a.x+b.x, a.y+b.y}; }

// o = a*b (2x2 complex, row-major)
__device__ inline void mm2(const C2* a, const C2* b, C2* o) {
    o[0] = cadd(cmul(a[0],b[0]), cmul(a[1],b[2]));
    o[1] = cadd(cmul(a[0],b[1]), cmul(a[1],b[3]));
    o[2] = cadd(cmul(a[2],b[0]), cmul(a[3],b[2]));
    o[3] = cadd(cmul(a[2],b[1]), cmul(a[3],b[3]));
}

__device__ inline void build_gate(int ty, float t, C2* g) {
    float sn, cs;
    __sincosf(0.5f * t, &sn, &cs);
    if (ty == 0) {        // rx
        g[0] = C2{cs, 0.f}; g[1] = C2{0.f, -sn};
        g[2] = C2{0.f, -sn}; g[3] = C2{cs, 0.f};
    } else if (ty == 1) { // ry
        g[0] = C2{cs, 0.f}; g[1] = C2{-sn, 0.f};
        g[2] = C2{sn, 0.f}; g[3] = C2{cs, 0.f};
    } else {              // rz
        g[0] = C2{cs, -sn}; g[1] = C2{0.f, 0.f};
        g[2] = C2{0.f, 0.f}; g[3] = C2{cs, sn};
    }
}

__device__ const int TYPES[5][3] = {
    {0,1,2},  // XYZ
    {1,2,1},  // YZY
    {2,1,0},  // ZYX
    {0,2,0},  // XZX
    {1,2,1},  // YZY
};

// bank-conflict swizzle: fold upper nibbles into low nibble (pure fn of high bits)
__device__ inline uint32_t slotf(uint32_t i){ return i ^ (((i>>4) ^ (i>>8) ^ (i>>12)) & 15u); }

template<int B> __device__ inline uint32_t ins0(uint32_t t){
    return ((t & ~((1u<<B)-1u)) << 1) | (t & ((1u<<B)-1u));
}
// deposit tid's 10 bits into the complement of group bits B0<B1<B2<B3 (final positions)
template<int B0,int B1,int B2,int B3> __device__ inline uint32_t expand4(uint32_t t){
    return ins0<B3>(ins0<B2>(ins0<B1>(ins0<B0>(t))));
}
template<int B0,int B1,int B2,int B3> __device__ inline uint32_t idx16(uint32_t base, int r){
    return base | ((r&1)?(1u<<B0):0u) | ((r&2)?(1u<<B1):0u)
                | ((r&4)?(1u<<B2):0u) | ((r&8)?(1u<<B3):0u);
}

template<int B0,int B1,int B2,int B3>
__device__ inline void gatherLDS(C2* v, const C2* s, uint32_t tid){
    uint32_t base = expand4<B0,B1,B2,B3>(tid);
    #pragma unroll
    for (int r = 0; r < 16; ++r) v[r] = s[slotf(idx16<B0,B1,B2,B3>(base, r))];
}
template<int B0,int B1,int B2,int B3>
__device__ inline void scatterLDS(const C2* v, C2* s, uint32_t tid){
    uint32_t base = expand4<B0,B1,B2,B3>(tid);
    #pragma unroll
    for (int r = 0; r < 16; ++r) s[slotf(idx16<B0,B1,B2,B3>(base, r))] = v[r];
}

// rotation on local bit J with fused 2x2 matrix g[0..3] (LDS broadcast reads)
template<int J>
__device__ inline void rotg(C2* v, const C2* g){
    const C2 m00 = g[0], m01 = g[1], m10 = g[2], m11 = g[3];
    #pragma unroll
    for (int r = 0; r < 16; ++r){
        if (!(r & (1 << J))) {
            C2 a0 = v[r], a1 = v[r | (1 << J)];
            v[r]          = cadd(cmul(m00, a0), cmul(m01, a1));
            v[r | (1<<J)] = cadd(cmul(m10, a0), cmul(m11, a1));
        }
    }
}
// CNOT: control local bit C, target local bit T
template<int C, int T>
__device__ inline void cnotg(C2* v){
    #pragma unroll
    for (int r = 0; r < 16; ++r){
        if ((r & (1 << C)) && !(r & (1 << T))) {
            C2 t = v[r]; v[r] = v[r | (1 << T)]; v[r | (1 << T)] = t;
        }
    }
}

__global__ __launch_bounds__(BLK) void qsim_kernel(
        const float* __restrict__ xr, const float* __restrict__ xi,
        const float* __restrict__ w, float* __restrict__ out) {
    __shared__ C2 s[DIM];          // 128 KiB statevector (swizzled layout)
    __shared__ C2 gm[5 * NQ * 4];  // 70 fused 2x2 complex gates
    __shared__ float red[BLK / 64];

    const int b   = blockIdx.x;
    const uint32_t tid = threadIdx.x;

    // ---- build fused gate matrices (threads 0..69) ----
    if (tid < 5 * NQ) {
        const int li = tid / NQ, q = tid % NQ;
        C2 M[4], G[4], T[4];
        #pragma unroll
        for (int j = 0; j < 3; ++j) {
            float t = w[3 * NQ * li + 3 * q + j] * WMUL;
            build_gate(TYPES[li][j], t, G);
            if (j == 0) { M[0]=G[0]; M[1]=G[1]; M[2]=G[2]; M[3]=G[3]; }
            else { mm2(G, M, T); M[0]=T[0]; M[1]=T[1]; M[2]=T[2]; M[3]=T[3]; }
        }
        #pragma unroll
        for (int k = 0; k < 4; ++k) gm[tid * 4 + k] = M[k];
    }
    __syncthreads();

    const float* xrb = xr + (size_t)b * DIM;
    const float* xib = xi + (size_t)b * DIM;

    C2 v[16];

    // qubit q <-> bit (13-q).  gm index: (li*NQ + q)*4
    #define GM(li, q) (&gm[((li) * NQ + (q)) * 4])

    for (int li = 0; li < 4; ++li) {
        // P1: bits {10,11,12,13} = qubits 3,2,1,0
        if (li == 0) {
            // first pass straight from global (coalesced: lanes vary low bits)
            #pragma unroll
            for (int r = 0; r < 16; ++r) {
                uint32_t i = tid | ((uint32_t)r << 10);
                v[r] = C2{xrb[i], xib[i]};
            }
        } else {
            gatherLDS<10,11,12,13>(v, s, tid);
        }
        rotg<3>(v, GM(li,0)); rotg<2>(v, GM(li,1)); rotg<1>(v, GM(li,2)); rotg<0>(v, GM(li,3));
        cnotg<3,2>(v); cnotg<2,1>(v); cnotg<1,0>(v);   // CNOT(0,1),(1,2),(2,3)
        scatterLDS<10,11,12,13>(v, s, tid);
        __syncthreads();

        // P2: bits {7,8,9,10} = qubits 6,5,4,3
        gatherLDS<7,8,9,10>(v, s, tid);
        rotg<2>(v, GM(li,4)); rotg<1>(v, GM(li,5)); rotg<0>(v, GM(li,6));
        cnotg<3,2>(v); cnotg<2,1>(v); cnotg<1,0>(v);   // CNOT(3,4),(4,5),(5,6)
        scatterLDS<7,8,9,10>(v, s, tid);
        __syncthreads();

        // P3: bits {4,5,6,7} = qubits 9,8,7,6
        gatherLDS<4,5,6,7>(v, s, tid);
        rotg<2>(v, GM(li,7)); rotg<1>(v, GM(li,8)); rotg<0>(v, GM(li,9));
        cnotg<3,2>(v); cnotg<2,1>(v); cnotg<1,0>(v);   // CNOT(6,7),(7,8),(8,9)
        scatterLDS<4,5,6,7>(v, s, tid);
        __syncthreads();

        // P4: bits {1,2,3,4} = qubits 12,11,10,9
        gatherLDS<1,2,3,4>(v, s, tid);
        rotg<2>(v, GM(li,10)); rotg<1>(v, GM(li,11)); rotg<0>(v, GM(li,12));
        cnotg<3,2>(v); cnotg<2,1>(v); cnotg<1,0>(v);   // CNOT(9,10),(10,11),(11,12)
        scatterLDS<1,2,3,4>(v, s, tid);
        __syncthreads();

        // P5: bits {0,1,2,13}: local0=q13, local1=q12, local2=q11(idle), local3=q0
        gatherLDS<0,1,2,13>(v, s, tid);
        rotg<0>(v, GM(li,13));
        cnotg<1,0>(v);   // CNOT(12,13)
        cnotg<0,3>(v);   // CNOT(13,0)
        scatterLDS<0,1,2,13>(v, s, tid);
        __syncthreads();
    }

    // ---- last layer (li=4): rotations only, 4 passes ----
    gatherLDS<10,11,12,13>(v, s, tid);
    rotg<3>(v, GM(4,0)); rotg<2>(v, GM(4,1)); rotg<1>(v, GM(4,2)); rotg<0>(v, GM(4,3));
    scatterLDS<10,11,12,13>(v, s, tid);
    __syncthreads();

    gatherLDS<6,7,8,9>(v, s, tid);
    rotg<3>(v, GM(4,4)); rotg<2>(v, GM(4,5)); rotg<1>(v, GM(4,6)); rotg<0>(v, GM(4,7));
    scatterLDS<6,7,8,9>(v, s, tid);
    __syncthreads();

    gatherLDS<2,3,4,5>(v, s, tid);
    rotg<3>(v, GM(4,8)); rotg<2>(v, GM(4,9)); rotg<1>(v, GM(4,10)); rotg<0>(v, GM(4,11));
    scatterLDS<2,3,4,5>(v, s, tid);
    __syncthreads();

    // final pass: bits {0,1,2,3}: local1=q12, local0=q13; fuse <Z_0> reduction
    gatherLDS<0,1,2,3>(v, s, tid);
    rotg<1>(v, GM(4,12)); rotg<0>(v, GM(4,13));

    // bit13 of this thread's indices = tid bit 9 (uniform per thread)
    float local = 0.f;
    #pragma unroll
    for (int r = 0; r < 16; ++r) local += v[r].x * v[r].x + v[r].y * v[r].y;
    if (tid & 512u) local = -local;

    #pragma unroll
    for (int off = 32; off > 0; off >>= 1) local += __shfl_down(local, off);
    const int lane = tid & 63, wid = tid >> 6;
    if (lane == 0) red[wid] = local;
    __syncthreads();
    if (tid == 0) {
        float t = 0.f;
        #pragma unroll
        for (int k = 0; k < BLK / 64; ++k) t += red[k];
        out[b] = t;
    }
}

extern "C" void kernel_launch(void* const* d_in, const int* in_sizes, int n_in,
                              void* d_out, int out_size, void* d_ws, size_t ws_size,
                              hipStream_t stream) {
    const float* xr = (const float*)d_in[0];
    const float* xi = (const float*)d_in[1];
    const float* w  = (const float*)d_in[2];
    float* out = (float*)d_out;
    const int B = out_size;  // 512
    qsim_kernel<<<B, BLK, 0, stream>>>(xr, xi, w, out);
}

// Round 3
// 380.200 us; speedup vs baseline: 1.0322x; 1.0322x over previous
//
#include <hip/hip_runtime.h>
#include <hip/hip_bf16.h>

#define NQ   14
#define DIM  16384      // 2^14
#define BLK  1024
#define WMUL 0.6324555320336759f  // sqrt(2/5)

struct alignas(8) C2 { float x, y; };
__device__ inline C2 cmul(C2 a, C2 b){ return C2{a.x*b.x - a.y*b.y, a.x*b.y + a.y*b.x}; }
__device__ inline C2 cadd(C2 a, C2 b){ return C2{a.x+b.x, a.y+b.y}; }

// o = a*b (2x2 complex, row-major)
__device__ inline void mm2(const C2* a, const C2* b, C2* o) {
    o[0] = cadd(cmul(a[0],b[0]), cmul(a[1],b[2]));
    o[1] = cadd(cmul(a[0],b[1]), cmul(a[1],b[3]));
    o[2] = cadd(cmul(a[2],b[0]), cmul(a[3],b[2]));
    o[3] = cadd(cmul(a[2],b[1]), cmul(a[3],b[3]));
}

__device__ inline void build_gate(int ty, float t, C2* g) {
    float sn, cs;
    __sincosf(0.5f * t, &sn, &cs);
    if (ty == 0) {        // rx
        g[0] = C2{cs, 0.f}; g[1] = C2{0.f, -sn};
        g[2] = C2{0.f, -sn}; g[3] = C2{cs, 0.f};
    } else if (ty == 1) { // ry
        g[0] = C2{cs, 0.f}; g[1] = C2{-sn, 0.f};
        g[2] = C2{sn, 0.f}; g[3] = C2{cs, 0.f};
    } else {              // rz
        g[0] = C2{cs, -sn}; g[1] = C2{0.f, 0.f};
        g[2] = C2{0.f, 0.f}; g[3] = C2{cs, sn};
    }
}

__device__ const int TYPES[5][3] = {
    {0,1,2},  // XYZ
    {1,2,1},  // YZY
    {2,1,0},  // ZYX
    {0,2,0},  // XZX
    {1,2,1},  // YZY
};

// bank-conflict swizzle: fold upper nibbles into low nibble (pure fn of high bits)
__device__ inline uint32_t slotf(uint32_t i){ return i ^ (((i>>4) ^ (i>>8) ^ (i>>12)) & 15u); }

template<int B> __device__ inline uint32_t ins0(uint32_t t){
    return ((t & ~((1u<<B)-1u)) << 1) | (t & ((1u<<B)-1u));
}
// deposit tid's 10 bits into the complement of group bits B0<B1<B2<B3 (final positions)
template<int B0,int B1,int B2,int B3> __device__ inline uint32_t expand4(uint32_t t){
    return ins0<B3>(ins0<B2>(ins0<B1>(ins0<B0>(t))));
}
template<int B0,int B1,int B2,int B3> __device__ inline uint32_t idx16(uint32_t base, int r){
    return base | ((r&1)?(1u<<B0):0u) | ((r&2)?(1u<<B1):0u)
                | ((r&4)?(1u<<B2):0u) | ((r&8)?(1u<<B3):0u);
}

template<int B0,int B1,int B2,int B3>
__device__ inline void gatherLDS(C2* __restrict__ v, const C2* __restrict__ s, uint32_t tid){
    uint32_t base = expand4<B0,B1,B2,B3>(tid);
    #pragma unroll
    for (int r = 0; r < 16; ++r) v[r] = s[slotf(idx16<B0,B1,B2,B3>(base, r))];
}
template<int B0,int B1,int B2,int B3>
__device__ inline void scatterLDS(const C2* __restrict__ v, C2* __restrict__ s, uint32_t tid){
    uint32_t base = expand4<B0,B1,B2,B3>(tid);
    #pragma unroll
    for (int r = 0; r < 16; ++r) s[slotf(idx16<B0,B1,B2,B3>(base, r))] = v[r];
}

// rotation on local bit J with fused 2x2 matrix g[0..3] (LDS broadcast reads)
template<int J>
__device__ inline void rotg(C2* v, const C2* g){
    const C2 m00 = g[0], m01 = g[1], m10 = g[2], m11 = g[3];
    #pragma unroll
    for (int r = 0; r < 16; ++r){
        if (!(r & (1 << J))) {
            C2 a0 = v[r], a1 = v[r | (1 << J)];
            v[r]          = cadd(cmul(m00, a0), cmul(m01, a1));
            v[r | (1<<J)] = cadd(cmul(m10, a0), cmul(m11, a1));
        }
    }
}
// CNOT: control local bit C, target local bit T
template<int C, int T>
__device__ inline void cnotg(C2* v){
    #pragma unroll
    for (int r = 0; r < 16; ++r){
        if ((r & (1 << C)) && !(r & (1 << T))) {
            C2 t = v[r]; v[r] = v[r | (1 << T)]; v[r | (1 << T)] = t;
        }
    }
}

// LDS 130 KiB/WG -> 1 WG/CU max -> 16 waves/CU = 4 waves/EU is the occupancy
// ceiling. Declare it so the allocator gets 512/4 = 128 VGPRs (64 spilled v[16]).
__global__ __launch_bounds__(BLK, 4) void qsim_kernel(
        const float* __restrict__ xr, const float* __restrict__ xi,
        const float* __restrict__ w, float* __restrict__ out) {
    __shared__ C2 s[DIM];          // 128 KiB statevector (swizzled layout)
    __shared__ C2 gm[5 * NQ * 4];  // 70 fused 2x2 complex gates
    __shared__ float red[BLK / 64];

    const int b   = blockIdx.x;
    const uint32_t tid = threadIdx.x;

    // ---- build fused gate matrices (threads 0..69) ----
    if (tid < 5 * NQ) {
        const int li = tid / NQ, q = tid % NQ;
        C2 M[4], G[4], T[4];
        #pragma unroll
        for (int j = 0; j < 3; ++j) {
            float t = w[3 * NQ * li + 3 * q + j] * WMUL;
            build_gate(TYPES[li][j], t, G);
            if (j == 0) { M[0]=G[0]; M[1]=G[1]; M[2]=G[2]; M[3]=G[3]; }
            else { mm2(G, M, T); M[0]=T[0]; M[1]=T[1]; M[2]=T[2]; M[3]=T[3]; }
        }
        #pragma unroll
        for (int k = 0; k < 4; ++k) gm[tid * 4 + k] = M[k];
    }
    __syncthreads();

    const float* xrb = xr + (size_t)b * DIM;
    const float* xib = xi + (size_t)b * DIM;

    C2 v[16];

    // qubit q <-> bit (13-q).  gm index: (li*NQ + q)*4
    #define GM(li, q) (&gm[((li) * NQ + (q)) * 4])

    for (int li = 0; li < 4; ++li) {
        // P1: bits {10,11,12,13} = qubits 3,2,1,0
        if (li == 0) {
            // first pass straight from global (coalesced: lanes vary low bits)
            #pragma unroll
            for (int r = 0; r < 16; ++r) {
                uint32_t i = tid | ((uint32_t)r << 10);
                v[r] = C2{xrb[i], xib[i]};
            }
        } else {
            gatherLDS<10,11,12,13>(v, s, tid);
        }
        rotg<3>(v, GM(li,0)); rotg<2>(v, GM(li,1)); rotg<1>(v, GM(li,2)); rotg<0>(v, GM(li,3));
        cnotg<3,2>(v); cnotg<2,1>(v); cnotg<1,0>(v);   // CNOT(0,1),(1,2),(2,3)
        scatterLDS<10,11,12,13>(v, s, tid);
        __syncthreads();

        // P2: bits {7,8,9,10} = qubits 6,5,4,3
        gatherLDS<7,8,9,10>(v, s, tid);
        rotg<2>(v, GM(li,4)); rotg<1>(v, GM(li,5)); rotg<0>(v, GM(li,6));
        cnotg<3,2>(v); cnotg<2,1>(v); cnotg<1,0>(v);   // CNOT(3,4),(4,5),(5,6)
        scatterLDS<7,8,9,10>(v, s, tid);
        __syncthreads();

        // P3: bits {4,5,6,7} = qubits 9,8,7,6
        gatherLDS<4,5,6,7>(v, s, tid);
        rotg<2>(v, GM(li,7)); rotg<1>(v, GM(li,8)); rotg<0>(v, GM(li,9));
        cnotg<3,2>(v); cnotg<2,1>(v); cnotg<1,0>(v);   // CNOT(6,7),(7,8),(8,9)
        scatterLDS<4,5,6,7>(v, s, tid);
        __syncthreads();

        // P4: bits {1,2,3,4} = qubits 12,11,10,9
        gatherLDS<1,2,3,4>(v, s, tid);
        rotg<2>(v, GM(li,10)); rotg<1>(v, GM(li,11)); rotg<0>(v, GM(li,12));
        cnotg<3,2>(v); cnotg<2,1>(v); cnotg<1,0>(v);   // CNOT(9,10),(10,11),(11,12)
        scatterLDS<1,2,3,4>(v, s, tid);
        __syncthreads();

        // P5: bits {0,1,2,13}: local0=q13, local1=q12, local2=q11(idle), local3=q0
        gatherLDS<0,1,2,13>(v, s, tid);
        rotg<0>(v, GM(li,13));
        cnotg<1,0>(v);   // CNOT(12,13)
        cnotg<0,3>(v);   // CNOT(13,0)
        scatterLDS<0,1,2,13>(v, s, tid);
        __syncthreads();
    }

    // ---- last layer (li=4): rotations only, 4 passes ----
    gatherLDS<10,11,12,13>(v, s, tid);
    rotg<3>(v, GM(4,0)); rotg<2>(v, GM(4,1)); rotg<1>(v, GM(4,2)); rotg<0>(v, GM(4,3));
    scatterLDS<10,11,12,13>(v, s, tid);
    __syncthreads();

    gatherLDS<6,7,8,9>(v, s, tid);
    rotg<3>(v, GM(4,4)); rotg<2>(v, GM(4,5)); rotg<1>(v, GM(4,6)); rotg<0>(v, GM(4,7));
    scatterLDS<6,7,8,9>(v, s, tid);
    __syncthreads();

    gatherLDS<2,3,4,5>(v, s, tid);
    rotg<3>(v, GM(4,8)); rotg<2>(v, GM(4,9)); rotg<1>(v, GM(4,10)); rotg<0>(v, GM(4,11));
    scatterLDS<2,3,4,5>(v, s, tid);
    __syncthreads();

    // final pass: bits {0,1,2,3}: local1=q12, local0=q13; fuse <Z_0> reduction
    gatherLDS<0,1,2,3>(v, s, tid);
    rotg<1>(v, GM(4,12)); rotg<0>(v, GM(4,13));

    // bit13 of this thread's indices = tid bit 9 (uniform per thread)
    float local = 0.f;
    #pragma unroll
    for (int r = 0; r < 16; ++r) local += v[r].x * v[r].x + v[r].y * v[r].y;
    if (tid & 512u) local = -local;

    #pragma unroll
    for (int off = 32; off > 0; off >>= 1) local += __shfl_down(local, off);
    const int lane = tid & 63, wid = tid >> 6;
    if (lane == 0) red[wid] = local;
    __syncthreads();
    if (tid == 0) {
        float t = 0.f;
        #pragma unroll
        for (int k = 0; k < BLK / 64; ++k) t += red[k];
        out[b] = t;
    }
}

extern "C" void kernel_launch(void* const* d_in, const int* in_sizes, int n_in,
                              void* d_out, int out_size, void* d_ws, size_t ws_size,
                              hipStream_t stream) {
    const float* xr = (const float*)d_in[0];
    const float* xi = (const float*)d_in[1];
    const float* w  = (const float*)d_in[2];
    float* out = (float*)d_out;
    const int B = out_size;  // 512
    qsim_kernel<<<B, BLK, 0, stream>>>(xr, xi, w, out);
}